// Round 10
// baseline (289.148 us; speedup 1.0000x reference)
//
#include <hip/hip_runtime.h>
#include <hip/hip_fp16.h>
#include <math.h>

#define NNODES 50000
#define NEDGES 500000
#define HID 128
#define NCLS 40

using short8v = __attribute__((ext_vector_type(8))) short;
using float4v = __attribute__((ext_vector_type(4))) float;

static __device__ __forceinline__ unsigned short f2bf(float f) {
    unsigned int u = __float_as_uint(f);
    u += 0x7FFFu + ((u >> 16) & 1u);   // RNE
    return (unsigned short)(u >> 16);
}
static __device__ __forceinline__ unsigned h2u(__half2 h) {
    union { __half2 h; unsigned u; } x; x.h = h; return x.u;
}
static __device__ __forceinline__ __half2 u2h(unsigned u) {
    union { unsigned u; __half2 h; } x; x.u = u; return x.h;
}

// ---------------------------------------------------------------------------
// prep_edges: rowptrs for A/B + interleaved {col, val-as-half2} streams
// ---------------------------------------------------------------------------
static __device__ __forceinline__ void rowptr_body(const int* __restrict__ row,
                                                   int e, int* __restrict__ rp) {
    if (e >= NEDGES) return;
    int r = row[e];
    int prev = (e == 0) ? -1 : row[e - 1];
    for (int q = prev + 1; q <= r; ++q) rp[q] = e;
    if (e == NEDGES - 1) {
        for (int q = r + 1; q <= NNODES; ++q) rp[q] = NEDGES;
    }
}

static __global__ void prep_edges_kernel(const int* __restrict__ arow,
                                         const int* __restrict__ acol,
                                         const float* __restrict__ aval,
                                         const int* __restrict__ brow,
                                         const int* __restrict__ bcol,
                                         const float* __restrict__ bval,
                                         const int* __restrict__ id,
                                         int* __restrict__ rpa, int* __restrict__ rpb,
                                         int2* __restrict__ cvA, int2* __restrict__ cvB,
                                         int gE) {
    int bid = blockIdx.x;
    if (bid < gE) {
        rowptr_body(arow, bid * 256 + threadIdx.x, rpa);
    } else if (bid < 2 * gE) {
        rowptr_body(brow, (bid - gE) * 256 + threadIdx.x, rpb);
    } else if (bid < 3 * gE) {
        int e = (bid - 2 * gE) * 256 + threadIdx.x;
        if (e < NEDGES) {
            __half2 v = __float2half2_rn(aval[e]);
            cvA[e] = make_int2(acol[e], (int)h2u(v));
        }
    } else {
        int e = (bid - 3 * gE) * 256 + threadIdx.x;
        if (e < NEDGES) {
            __half2 v = __float2half2_rn(bval[e]);
            cvB[e] = make_int2(id[bcol[e]], (int)h2u(v));
        }
    }
}

// ---------------------------------------------------------------------------
// prep_x: x0b = bf16(x0); xmb = bf16(r*x0 + (1-r)*x0[id])
// ---------------------------------------------------------------------------
static __global__ void prep_x_kernel(const float4* __restrict__ x, const int* __restrict__ id,
                                     const float* __restrict__ mixr,
                                     uint2* __restrict__ x0b, uint2* xmb) {
    int i = blockIdx.x * blockDim.x + threadIdx.x;   // exactly N*HID/4
    int n = i >> 5, qq = i & 31;
    float r = mixr[0];
    float4 a = x[i];
    float4 b = x[(size_t)id[n] * 32 + qq];
    uint2 pa, pm;
    pa.x = (unsigned)f2bf(a.x) | ((unsigned)f2bf(a.y) << 16);
    pa.y = (unsigned)f2bf(a.z) | ((unsigned)f2bf(a.w) << 16);
    pm.x = (unsigned)f2bf(r * a.x + (1.f - r) * b.x) |
           ((unsigned)f2bf(r * a.y + (1.f - r) * b.y) << 16);
    pm.y = (unsigned)f2bf(r * a.z + (1.f - r) * b.z) |
           ((unsigned)f2bf(r * a.w + (1.f - r) * b.w) << 16);
    x0b[i] = pa;
    xmb[i] = pm;
}

// ---------------------------------------------------------------------------
// prep_w: Wt[mat][n][k] for 6 mats (0-2 Wl, 3-5 Wr), then WoT[c][k] (48-pad)
// ---------------------------------------------------------------------------
static __global__ void prep_w_kernel(const float* __restrict__ Wl, const float* __restrict__ Wr,
                                     const float* __restrict__ Wout,
                                     unsigned short* __restrict__ Wt,
                                     unsigned short* __restrict__ WoT) {
    int t = blockIdx.x * blockDim.x + threadIdx.x;   // exactly 6*16384 + 48*128
    if (t < 6 * 16384) {
        int mat = t >> 14, idx = t & 16383;
        int n = idx >> 7, k = idx & 127;
        const float* src = (mat < 3) ? (Wl + mat * 16384) : (Wr + (mat - 3) * 16384);
        Wt[t] = f2bf(src[k * HID + n]);
    } else {
        int u = t - 6 * 16384;
        int c = u >> 7, k = u & 127;
        WoT[u] = (c < NCLS) ? f2bf(Wout[k * NCLS + c]) : (unsigned short)0;
    }
}

// ---------------------------------------------------------------------------
// MFMA helpers: swapped-operand layout (D[row=lane&15][col=tile*16+(lane>>4)*4+i])
// ---------------------------------------------------------------------------
#define LOAD_W4(ptr, w0, w1, w2, w3)                                            \
    w0 = *(const short8v*)(ptr);                                                \
    w1 = *(const short8v*)((ptr) + 32);                                         \
    w2 = *(const short8v*)((ptr) + 64);                                         \
    w3 = *(const short8v*)((ptr) + 96);

#define MFMA4(w0, w1, w2, w3, x0, x1, x2, x3, t)                                \
    t = __builtin_amdgcn_mfma_f32_16x16x32_bf16(w0, x0, t, 0, 0, 0);            \
    t = __builtin_amdgcn_mfma_f32_16x16x32_bf16(w1, x1, t, 0, 0, 0);            \
    t = __builtin_amdgcn_mfma_f32_16x16x32_bf16(w2, x2, t, 0, 0, 0);            \
    t = __builtin_amdgcn_mfma_f32_16x16x32_bf16(w3, x3, t, 0, 0, 0);

// gemm_y: y0 = A @ Wt^T (f16 out). One wave per 16 rows, front-loaded W tiles.
static __global__ __launch_bounds__(64, 2) void gemm_y_kernel(
    const unsigned short* __restrict__ A, const unsigned short* __restrict__ Wt,
    __half* __restrict__ out) {
    const int lr = threadIdx.x & 15;
    const int lg = threadIdx.x >> 4;
    const int row = blockIdx.x * 16 + lr;
    const size_t rbase = (size_t)row * HID;
    const unsigned short* ap = A + rbase + lg * 8;
    short8v a0 = *(const short8v*)(ap);
    short8v a1 = *(const short8v*)(ap + 32);
    short8v a2 = *(const short8v*)(ap + 64);
    short8v a3 = *(const short8v*)(ap + 96);
    const unsigned short* wb = Wt + (size_t)lr * HID + lg * 8;
    short8v q0[4], q1[4], q2[4], q3[4];
    LOAD_W4(wb + 0 * 2048, q0[0], q0[1], q0[2], q0[3])
    LOAD_W4(wb + 1 * 2048, q1[0], q1[1], q1[2], q1[3])
    LOAD_W4(wb + 2 * 2048, q2[0], q2[1], q2[2], q2[3])
    LOAD_W4(wb + 3 * 2048, q3[0], q3[1], q3[2], q3[3])
    __builtin_amdgcn_sched_barrier(0);
#define GY_TILE(c, W, refill)                                                   \
    {                                                                           \
        float4v t = {0.f, 0.f, 0.f, 0.f};                                       \
        MFMA4(W[0], W[1], W[2], W[3], a0, a1, a2, a3, t)                        \
        __half2 p01 = __floats2half2_rn(t[0], t[1]);                            \
        __half2 p23 = __floats2half2_rn(t[2], t[3]);                            \
        uint2 o; o.x = h2u(p01); o.y = h2u(p23);                                \
        *(uint2*)(out + rbase + (c) * 16 + lg * 4) = o;                         \
        if ((refill) >= 0) {                                                    \
            LOAD_W4(wb + (size_t)(refill) * 2048, W[0], W[1], W[2], W[3])       \
        }                                                                       \
    }
    GY_TILE(0, q0, 4) GY_TILE(1, q1, 5) GY_TILE(2, q2, 6) GY_TILE(3, q3, 7)
    GY_TILE(4, q0, -1) GY_TILE(5, q1, -1) GY_TILE(6, q2, -1) GY_TILE(7, q3, -1)
#undef GY_TILE
}

// ---------------------------------------------------------------------------
// layer_kernel<DO_HY>: merged SpMM + SAGE layer. Block = 256 thr / 16 nodes.
// Phase 1: quarter-wave qw gathers node (blk*16+qw)'s A & B rows from yIn
//          (dual stream, cv 1-ahead, f16 hfma2) -> Sls/Tls in LDS only.
// Phase 2: 4 waves col-split (2 tiles each): z = xm@Wr + b;
//          DO_HY: hv = relu(S + Ah@Wr + b); xm' = r*relu(S+z)+(1-r)*relu(T+z)
//          DO_HY: store xm',h; h->hs; y' = h@WtLn -> yOut (ping-pong!)
//          !DO_HY: xm'->hs; head: logits = xm'@WoT + bout; log_softmax -> out
// ---------------------------------------------------------------------------
template <bool DO_HY>
static __global__ __launch_bounds__(256, 3) void layer_kernel(
    const __half* __restrict__ yIn,
    const int2* __restrict__ cvA, const int* __restrict__ rpA,
    const int2* __restrict__ cvB, const int* __restrict__ rpB,
    const unsigned short* __restrict__ Ah,
    unsigned short* xm,
    const unsigned short* __restrict__ WtR,
    const unsigned short* __restrict__ WtLn,
    const float* __restrict__ bias, const float* __restrict__ mixr,
    unsigned short* __restrict__ hOut, __half* __restrict__ yOut,
    const unsigned short* __restrict__ WoT, const float* __restrict__ bout,
    float* __restrict__ out) {
    __shared__ __align__(16) __half Sls[16][136];
    __shared__ __align__(16) __half Tls[16][136];
    __shared__ __align__(16) unsigned short hs[16][136];
    __shared__ float lgt[16][52];
    __shared__ float lse_s[16];

    const int tid = threadIdx.x;
    const int lr = tid & 15;
    const int lg = (tid >> 4) & 3;
    const int wv = tid >> 6;
    const int row = blockIdx.x * 16 + lr;     // grid = N/16 exact
    const size_t rbase = (size_t)row * HID;
    const float rr = mixr[0];

    // ======== phase-2 operand preload (independent of phase 1) ========
    const unsigned short* xp = xm + rbase + lg * 8;
    short8v ax0 = *(const short8v*)(xp);
    short8v ax1 = *(const short8v*)(xp + 32);
    short8v ax2 = *(const short8v*)(xp + 64);
    short8v ax3 = *(const short8v*)(xp + 96);
    short8v ah0, ah1, ah2, ah3;
    if constexpr (DO_HY) {
        const unsigned short* hp = Ah + rbase + lg * 8;
        ah0 = *(const short8v*)(hp);
        ah1 = *(const short8v*)(hp + 32);
        ah2 = *(const short8v*)(hp + 64);
        ah3 = *(const short8v*)(hp + 96);
    }
    // this wave's 2 W col-tiles of WtR: rows wv*32+lr and wv*32+16+lr
    const unsigned short* wrb = WtR + (size_t)(wv * 32 + lr) * HID + lg * 8;
    short8v w00, w01, w02, w03, w10, w11, w12, w13;
    LOAD_W4(wrb, w00, w01, w02, w03)
    LOAD_W4(wrb + 16 * HID, w10, w11, w12, w13)
    __builtin_amdgcn_sched_barrier(0);

    // ======== phase 1: dual-stream SpMM gather for node blk*16+qw ========
    {
        const int qw = tid >> 4;
        const int j = tid & 15;
        const int node = blockIdx.x * 16 + qw;
        int eA = rpA[node];
        const int aE = rpA[node + 1];
        int eB = rpB[node];
        const int bE = rpB[node + 1];
        const __half2 hz = __float2half2_rn(0.f);
        __half2 sa0 = hz, sa1 = hz, sa2 = hz, sa3 = hz;
        __half2 ta0 = hz, ta1 = hz, ta2 = hz, ta3 = hz;
        int2 mA = cvA[min(eA, NEDGES - 1)];
        int2 mB = cvB[min(eB, NEDGES - 1)];
        while (eA < aE || eB < bE) {
            const bool vA = eA < aE, vB = eB < bE;
            const int eA2 = eA + (vA ? 1 : 0);
            const int eB2 = eB + (vB ? 1 : 0);
            const int2 nA = cvA[min(eA2, NEDGES - 1)];
            const int2 nB = cvB[min(eB2, NEDGES - 1)];
            const uint4 pA = *(const uint4*)(yIn + (size_t)mA.x * HID + j * 8);
            const uint4 pB = *(const uint4*)(yIn + (size_t)mB.x * HID + j * 8);
            const __half2 vvA = vA ? u2h((unsigned)mA.y) : hz;
            const __half2 vvB = vB ? u2h((unsigned)mB.y) : hz;
            sa0 = __hfma2(u2h(pA.x), vvA, sa0); sa1 = __hfma2(u2h(pA.y), vvA, sa1);
            sa2 = __hfma2(u2h(pA.z), vvA, sa2); sa3 = __hfma2(u2h(pA.w), vvA, sa3);
            ta0 = __hfma2(u2h(pB.x), vvB, ta0); ta1 = __hfma2(u2h(pB.y), vvB, ta1);
            ta2 = __hfma2(u2h(pB.z), vvB, ta2); ta3 = __hfma2(u2h(pB.w), vvB, ta3);
            mA = nA; mB = nB; eA = eA2; eB = eB2;
        }
        uint4 os, ot;
        os.x = h2u(sa0); os.y = h2u(sa1); os.z = h2u(sa2); os.w = h2u(sa3);
        ot.x = h2u(ta0); ot.y = h2u(ta1); ot.z = h2u(ta2); ot.w = h2u(ta3);
        *(uint4*)&Sls[qw][j * 8] = os;
        *(uint4*)&Tls[qw][j * 8] = ot;
    }
    __syncthreads();

    // ======== phase 2: z (+h) MFMA, 2 col-tiles per wave ========
    float4v accz[2], acch[2];
    {
        float4v t = {0.f, 0.f, 0.f, 0.f};
        MFMA4(w00, w01, w02, w03, ax0, ax1, ax2, ax3, t)
        accz[0] = t;
        if constexpr (DO_HY) {
            float4v u = {0.f, 0.f, 0.f, 0.f};
            MFMA4(w00, w01, w02, w03, ah0, ah1, ah2, ah3, u)
            acch[0] = u;
        }
    }
    {
        float4v t = {0.f, 0.f, 0.f, 0.f};
        MFMA4(w10, w11, w12, w13, ax0, ax1, ax2, ax3, t)
        accz[1] = t;
        if constexpr (DO_HY) {
            float4v u = {0.f, 0.f, 0.f, 0.f};
            MFMA4(w10, w11, w12, w13, ah0, ah1, ah2, ah3, u)
            acch[1] = u;
        }
    }
    // preload WtLn tiles for the y-GEMM (hidden under epilogue)
    short8v y00, y01, y02, y03, y10, y11, y12, y13;
    if constexpr (DO_HY) {
        const unsigned short* wlb = WtLn + (size_t)(wv * 32 + lr) * HID + lg * 8;
        LOAD_W4(wlb, y00, y01, y02, y03)
        LOAD_W4(wlb + 16 * HID, y10, y11, y12, y13)
    }

    // ======== epilogue: S/T from LDS, mix, stores ========
#pragma unroll
    for (int c = 0; c < 2; ++c) {
        const int col0 = (wv * 2 + c) * 16 + lg * 4;
        const float4v bv = *(const float4v*)(bias + col0);
        const uint2 svu = *(const uint2*)&Sls[lr][col0];
        const uint2 tvu = *(const uint2*)&Tls[lr][col0];
        const float2 s01 = __half22float2(u2h(svu.x));
        const float2 s23 = __half22float2(u2h(svu.y));
        const float2 t01 = __half22float2(u2h(tvu.x));
        const float2 t23 = __half22float2(u2h(tvu.y));
        const float s4[4] = {s01.x, s01.y, s23.x, s23.y};
        const float t4[4] = {t01.x, t01.y, t23.x, t23.y};
        unsigned short xm4[4], h4[4];
#pragma unroll
        for (int i = 0; i < 4; ++i) {
            const float z = accz[c][i] + bv[i];
            const float xa = fmaxf(s4[i] + z, 0.f);
            const float xb = fmaxf(t4[i] + z, 0.f);
            xm4[i] = f2bf(rr * xa + (1.f - rr) * xb);
            if constexpr (DO_HY) h4[i] = f2bf(fmaxf(acch[c][i] + s4[i] + bv[i], 0.f));
        }
        uint2 xmv;
        xmv.x = (unsigned)xm4[0] | ((unsigned)xm4[1] << 16);
        xmv.y = (unsigned)xm4[2] | ((unsigned)xm4[3] << 16);
        if constexpr (DO_HY) {
            uint2 hv;
            hv.x = (unsigned)h4[0] | ((unsigned)h4[1] << 16);
            hv.y = (unsigned)h4[2] | ((unsigned)h4[3] << 16);
            *(uint2*)(xm + rbase + col0) = xmv;
            *(uint2*)(hOut + rbase + col0) = hv;
            *(uint2*)(&hs[lr][col0]) = hv;
        } else {
            *(uint2*)(&hs[lr][col0]) = xmv;
        }
    }
    __syncthreads();

    // ======== stage 3: full-K frags from hs ========
    const unsigned short* lp = &hs[lr][lg * 8];
    short8v c0 = *(const short8v*)(lp);
    short8v c1 = *(const short8v*)(lp + 32);
    short8v c2 = *(const short8v*)(lp + 64);
    short8v c3 = *(const short8v*)(lp + 96);

    if constexpr (DO_HY) {
        // y' = h @ WtLn, 2 tiles per wave -> ping-pong output buffer
        {
            float4v t = {0.f, 0.f, 0.f, 0.f};
            MFMA4(y00, y01, y02, y03, c0, c1, c2, c3, t)
            __half2 p01 = __floats2half2_rn(t[0], t[1]);
            __half2 p23 = __floats2half2_rn(t[2], t[3]);
            uint2 o; o.x = h2u(p01); o.y = h2u(p23);
            *(uint2*)(yOut + rbase + (wv * 2) * 16 + lg * 4) = o;
        }
        {
            float4v t = {0.f, 0.f, 0.f, 0.f};
            MFMA4(y10, y11, y12, y13, c0, c1, c2, c3, t)
            __half2 p01 = __floats2half2_rn(t[0], t[1]);
            __half2 p23 = __floats2half2_rn(t[2], t[3]);
            uint2 o; o.x = h2u(p01); o.y = h2u(p23);
            *(uint2*)(yOut + rbase + (wv * 2 + 1) * 16 + lg * 4) = o;
        }
    } else {
        // head: waves 0-2 compute one 16-col logits tile each (cols 0..47)
        if (wv < 3) {
            const unsigned short* wq = WoT + (size_t)(wv * 16 + lr) * HID + lg * 8;
            short8v w0, w1, w2, w3;
            LOAD_W4(wq, w0, w1, w2, w3)
            float4v t = {0.f, 0.f, 0.f, 0.f};
            MFMA4(w0, w1, w2, w3, c0, c1, c2, c3, t)
            const int col0 = wv * 16 + lg * 4;
            if (col0 < NCLS) {
#pragma unroll
                for (int i = 0; i < 4; ++i)
                    lgt[lr][col0 + i] = t[i] + bout[col0 + i];
            }
        }
        __syncthreads();
        if (tid < 16) {
            const int r = tid;
            float mx = -INFINITY;
#pragma unroll 4
            for (int j = 0; j < NCLS; ++j) mx = fmaxf(mx, lgt[r][j]);
            float s = 0.f;
#pragma unroll 4
            for (int j = 0; j < NCLS; ++j) s += expf(lgt[r][j] - mx);
            lse_s[r] = mx + logf(s);
        }
        __syncthreads();
        const int gr0 = blockIdx.x * 16;
        for (int idx = tid; idx < 16 * NCLS; idx += 256) {
            const int r = idx / NCLS;
            const int cc = idx - r * NCLS;
            out[(size_t)(gr0 + r) * NCLS + cc] = lgt[r][cc] - lse_s[r];
        }
    }
}

// ---------------------------------------------------------------------------
extern "C" void kernel_launch(void* const* d_in, const int* in_sizes, int n_in,
                              void* d_out, int out_size, void* d_ws, size_t ws_size,
                              hipStream_t stream) {
    const float* x0   = (const float*)d_in[0];
    const int*   arow = (const int*)d_in[1];
    const int*   acol = (const int*)d_in[2];
    const float* aval = (const float*)d_in[3];
    const int*   brow = (const int*)d_in[4];
    const int*   bcol = (const int*)d_in[5];
    const float* bval = (const float*)d_in[6];
    const float* mixr = (const float*)d_in[7];
    const int*   id   = (const int*)d_in[8];
    const float* Wl   = (const float*)d_in[9];
    const float* Wr   = (const float*)d_in[10];
    const float* bs   = (const float*)d_in[11];
    const float* Wout = (const float*)d_in[12];
    const float* bout = (const float*)d_in[13];
    float* out = (float*)d_out;

    const size_t NF = (size_t)NNODES * HID;   // 6.4M
    unsigned short* x0b = (unsigned short*)d_ws;
    unsigned short* xmb = x0b + NF;
    unsigned short* h1b = xmb + NF;
    unsigned short* h2b = h1b + NF;
    __half* yA = (__half*)(h2b + NF);
    __half* yB = yA + NF;
    unsigned short* Wt  = (unsigned short*)(yB + NF);  // 6 * 16384 bf16
    unsigned short* WoT = Wt + 6 * 16384;               // 48 * 128 bf16
    int2* cvA = (int2*)(WoT + 48 * 128);                 // E int2
    int2* cvB = cvA + NEDGES;
    int* rpa = (int*)(cvB + NEDGES);
    int* rpb = rpa + (NNODES + 1);

    const int gE = (NEDGES + 255) / 256;      // 1954
    const int gC = NNODES * HID / 4 / 256;    // 6250
    const int gG = NNODES / 16;               // 3125 (exact)

    prep_edges_kernel<<<4 * gE, 256, 0, stream>>>(arow, acol, aval, brow, bcol, bval,
                                                  id, rpa, rpb, cvA, cvB, gE);
    prep_x_kernel<<<gC, 256, 0, stream>>>((const float4*)x0, id, mixr, (uint2*)x0b, (uint2*)xmb);
    prep_w_kernel<<<(6 * 16384 + 48 * 128) / 256, 256, 0, stream>>>(Wl, Wr, Wout, Wt, WoT);

    // y0 = x0 @ Wl0
    gemm_y_kernel<<<gG, 64, 0, stream>>>(x0b, Wt + 0 * 16384, yA);

    // ---- layer 0: gathers yA, writes h1, xm, yB
    layer_kernel<true><<<gG, 256, 0, stream>>>(
        yA, cvA, rpa, cvB, rpb, x0b, xmb,
        Wt + 3 * 16384, Wt + 1 * 16384, bs, mixr,
        h1b, yB, nullptr, nullptr, nullptr);

    // ---- layer 1: gathers yB, writes h2, xm, yA
    layer_kernel<true><<<gG, 256, 0, stream>>>(
        yB, cvA, rpa, cvB, rpb, h1b, xmb,
        Wt + 4 * 16384, Wt + 2 * 16384, bs + 128, mixr,
        h2b, yA, nullptr, nullptr, nullptr);

    // ---- layer 2 (+ head): gathers yA, writes out
    layer_kernel<false><<<gG, 256, 0, stream>>>(
        yA, cvA, rpa, cvB, rpb, nullptr, xmb,
        Wt + 5 * 16384, nullptr, bs + 256, mixr,
        nullptr, nullptr, WoT, bout, out);
}

// Round 12
// 254.326 us; speedup vs baseline: 1.1369x; 1.1369x over previous
//
#include <hip/hip_runtime.h>
#include <hip/hip_fp16.h>
#include <math.h>

#define NNODES 50000
#define NEDGES 500000
#define HID 128
#define NCLS 40

using half8v = __attribute__((ext_vector_type(8))) _Float16;
using float4v = __attribute__((ext_vector_type(4))) float;
using uint4v = __attribute__((ext_vector_type(4))) unsigned;

static __device__ __forceinline__ unsigned h2u(__half2 h) {
    union { __half2 h; unsigned u; } x; x.h = h; return x.u;
}
static __device__ __forceinline__ __half2 u2h(unsigned u) {
    union { unsigned u; __half2 h; } x; x.u = u; return x.h;
}

// ---------------------------------------------------------------------------
// prep_edges: rowptrs for A/B + interleaved {col, val-as-half2} streams
// ---------------------------------------------------------------------------
static __device__ __forceinline__ void rowptr_body(const int* __restrict__ row,
                                                   int e, int* __restrict__ rp) {
    if (e >= NEDGES) return;
    int r = row[e];
    int prev = (e == 0) ? -1 : row[e - 1];
    for (int q = prev + 1; q <= r; ++q) rp[q] = e;
    if (e == NEDGES - 1) {
        for (int q = r + 1; q <= NNODES; ++q) rp[q] = NEDGES;
    }
}

static __global__ void prep_edges_kernel(const int* __restrict__ arow,
                                         const int* __restrict__ acol,
                                         const float* __restrict__ aval,
                                         const int* __restrict__ brow,
                                         const int* __restrict__ bcol,
                                         const float* __restrict__ bval,
                                         const int* __restrict__ id,
                                         int* __restrict__ rpa, int* __restrict__ rpb,
                                         int2* __restrict__ cvA, int2* __restrict__ cvB,
                                         int gE) {
    int bid = blockIdx.x;
    if (bid < gE) {
        rowptr_body(arow, bid * 256 + threadIdx.x, rpa);
    } else if (bid < 2 * gE) {
        rowptr_body(brow, (bid - gE) * 256 + threadIdx.x, rpb);
    } else if (bid < 3 * gE) {
        int e = (bid - 2 * gE) * 256 + threadIdx.x;
        if (e < NEDGES) {
            __half2 v = __float2half2_rn(aval[e]);
            cvA[e] = make_int2(acol[e], (int)h2u(v));
        }
    } else {
        int e = (bid - 3 * gE) * 256 + threadIdx.x;
        if (e < NEDGES) {
            __half2 v = __float2half2_rn(bval[e]);
            cvB[e] = make_int2(id[bcol[e]], (int)h2u(v));
        }
    }
}

// ---------------------------------------------------------------------------
// prep_x: x0h = f16(x0); xmh = f16(r*x0 + (1-r)*x0[id])
// ---------------------------------------------------------------------------
static __global__ void prep_x_kernel(const float4* __restrict__ x, const int* __restrict__ id,
                                     const float* __restrict__ mixr,
                                     uint2* __restrict__ x0h, uint2* xmh) {
    int i = blockIdx.x * blockDim.x + threadIdx.x;   // exactly N*HID/4
    int n = i >> 5, qq = i & 31;
    float r = mixr[0];
    float4 a = x[i];
    float4 b = x[(size_t)id[n] * 32 + qq];
    uint2 pa, pm;
    pa.x = h2u(__floats2half2_rn(a.x, a.y));
    pa.y = h2u(__floats2half2_rn(a.z, a.w));
    pm.x = h2u(__floats2half2_rn(r * a.x + (1.f - r) * b.x, r * a.y + (1.f - r) * b.y));
    pm.y = h2u(__floats2half2_rn(r * a.z + (1.f - r) * b.z, r * a.w + (1.f - r) * b.w));
    x0h[i] = pa;
    xmh[i] = pm;
}

// ---------------------------------------------------------------------------
// prep_w: Wt[mat][n][k] f16 for 6 mats (0-2 Wl, 3-5 Wr), then WoT[c][k] 48-pad
// ---------------------------------------------------------------------------
static __global__ void prep_w_kernel(const float* __restrict__ Wl, const float* __restrict__ Wr,
                                     const float* __restrict__ Wout,
                                     __half* __restrict__ Wt, __half* __restrict__ WoT) {
    int t = blockIdx.x * blockDim.x + threadIdx.x;   // exactly 6*16384 + 48*128
    if (t < 6 * 16384) {
        int mat = t >> 14, idx = t & 16383;
        int n = idx >> 7, k = idx & 127;
        const float* src = (mat < 3) ? (Wl + mat * 16384) : (Wr + (mat - 3) * 16384);
        Wt[t] = __float2half(src[k * HID + n]);
    } else {
        int u = t - 6 * 16384;
        int c = u >> 7, k = u & 127;
        WoT[u] = (c < NCLS) ? __float2half(Wout[k * NCLS + c]) : __float2half(0.f);
    }
}

// ---------------------------------------------------------------------------
// spmm2: wave w<N -> Sh[w,:] via A edges; w>=N -> Th via B edges (h f16 in/out).
// Quarter-wave (16 lanes x 16B) per row gather, unroll x2 -> 8 rows in flight,
// __hfma2 accumulate, non-temporal output stores.
// ---------------------------------------------------------------------------
static __global__ __launch_bounds__(256) void spmm2_kernel(
    const __half* __restrict__ h,
    const int2* __restrict__ cvA, const int* __restrict__ rpA,
    __half* __restrict__ Sh,
    const int2* __restrict__ cvB, const int* __restrict__ rpB,
    __half* __restrict__ Th) {
    int w = blockIdx.x * 4 + (threadIdx.x >> 6);
    const int l = threadIdx.x & 63;
    const int q = l >> 4, j = l & 15;
    const int2* cv; const int* rp; __half* dst; int node;
    if (w < NNODES) { cv = cvA; rp = rpA; dst = Sh; node = w; }
    else            { cv = cvB; rp = rpB; dst = Th; node = w - NNODES; }
    const int e0 = rp[node], e1 = rp[node + 1];
    __half2 a0 = __float2half2_rn(0.f), a1 = a0, a2 = a0, a3 = a0;
    int e = e0 + q;
    int2 m0, m1;
    bool have = (e + 4 < e1);
    if (have) { m0 = cv[e]; m1 = cv[e + 4]; }
    while (have) {
        const int e2 = e + 8;
        const bool nxt = (e2 + 4 < e1);
        int2 k0 = m0, k1 = m1;
        if (nxt) { k0 = cv[e2]; k1 = cv[e2 + 4]; }
        const uint4 p0 = *(const uint4*)(h + (size_t)m0.x * HID + j * 8);
        const uint4 p1 = *(const uint4*)(h + (size_t)m1.x * HID + j * 8);
        const __half2 v0 = u2h((unsigned)m0.y), v1 = u2h((unsigned)m1.y);
        a0 = __hfma2(u2h(p0.x), v0, a0); a1 = __hfma2(u2h(p0.y), v0, a1);
        a2 = __hfma2(u2h(p0.z), v0, a2); a3 = __hfma2(u2h(p0.w), v0, a3);
        a0 = __hfma2(u2h(p1.x), v1, a0); a1 = __hfma2(u2h(p1.y), v1, a1);
        a2 = __hfma2(u2h(p1.z), v1, a2); a3 = __hfma2(u2h(p1.w), v1, a3);
        m0 = k0; m1 = k1; e = e2; have = nxt;
    }
    if (e < e1) {
        const int2 m = cv[e];
        const uint4 p = *(const uint4*)(h + (size_t)m.x * HID + j * 8);
        const __half2 v = u2h((unsigned)m.y);
        a0 = __hfma2(u2h(p.x), v, a0); a1 = __hfma2(u2h(p.y), v, a1);
        a2 = __hfma2(u2h(p.z), v, a2); a3 = __hfma2(u2h(p.w), v, a3);
    }
    a0 = __hadd2(a0, u2h(__shfl_xor((int)h2u(a0), 16)));
    a1 = __hadd2(a1, u2h(__shfl_xor((int)h2u(a1), 16)));
    a2 = __hadd2(a2, u2h(__shfl_xor((int)h2u(a2), 16)));
    a3 = __hadd2(a3, u2h(__shfl_xor((int)h2u(a3), 16)));
    a0 = __hadd2(a0, u2h(__shfl_xor((int)h2u(a0), 32)));
    a1 = __hadd2(a1, u2h(__shfl_xor((int)h2u(a1), 32)));
    a2 = __hadd2(a2, u2h(__shfl_xor((int)h2u(a2), 32)));
    a3 = __hadd2(a3, u2h(__shfl_xor((int)h2u(a3), 32)));
    if (l < 16) {
        uint4v o;
        o.x = h2u(a0); o.y = h2u(a1); o.z = h2u(a2); o.w = h2u(a3);
        __builtin_nontemporal_store(o, (uint4v*)(dst + (size_t)node * HID + l * 8));
    }
}

// ---------------------------------------------------------------------------
// Swapped-operand f16 MFMA: D[row = lane&15][col = tile*16 + (lane>>4)*4 + i]
// ---------------------------------------------------------------------------
#define LOAD_H4(ptr, w0, w1, w2, w3)                                            \
    w0 = *(const half8v*)(ptr);                                                 \
    w1 = *(const half8v*)((ptr) + 32);                                          \
    w2 = *(const half8v*)((ptr) + 64);                                          \
    w3 = *(const half8v*)((ptr) + 96);

#define LOAD_H4NT(ptr, w0, w1, w2, w3)                                          \
    w0 = __builtin_nontemporal_load((const half8v*)(ptr));                      \
    w1 = __builtin_nontemporal_load((const half8v*)((ptr) + 32));               \
    w2 = __builtin_nontemporal_load((const half8v*)((ptr) + 64));               \
    w3 = __builtin_nontemporal_load((const half8v*)((ptr) + 96));

#define MFMA4(w0, w1, w2, w3, x0, x1, x2, x3, t)                                \
    t = __builtin_amdgcn_mfma_f32_16x16x32_f16(w0, x0, t, 0, 0, 0);             \
    t = __builtin_amdgcn_mfma_f32_16x16x32_f16(w1, x1, t, 0, 0, 0);             \
    t = __builtin_amdgcn_mfma_f32_16x16x32_f16(w2, x2, t, 0, 0, 0);             \
    t = __builtin_amdgcn_mfma_f32_16x16x32_f16(w3, x3, t, 0, 0, 0);

// ---------------------------------------------------------------------------
// fused_layer<DO_HY>: one wave per 16 rows, re-associated layer math.
//   S = Sh@Wl; T = Th@Wl; z = xm@Wr + b; DO_HY: hz = h@Wr
//   h' = relu(S + hz + b);  xm' = r*relu(S+z) + (1-r)*relu(T+z)
//   !DO_HY: xm' -> LDS; head: logits = xm'@WoT + bout; log_softmax -> out
// ---------------------------------------------------------------------------
template <bool DO_HY>
static __global__ __launch_bounds__(64, 2) void fused_layer_kernel(
    const __half* __restrict__ Sh, const __half* __restrict__ Th,
    __half* xm, const __half* __restrict__ hIn,
    const __half* __restrict__ Wl, const __half* __restrict__ Wr,
    const float* __restrict__ bias, const float* __restrict__ mixr,
    __half* __restrict__ hOut,
    const __half* __restrict__ WoT, const float* __restrict__ bout,
    float* __restrict__ out) {
    __shared__ __align__(16) __half hs[16][136];
    const int lr = threadIdx.x & 15;
    const int lg = threadIdx.x >> 4;
    const int row = blockIdx.x * 16 + lr;
    const size_t rbase = (size_t)row * HID;
    const float rr = mixr[0];

    // ---- front-load the 4 A-streams (16 independent 16B loads)
    half8v sh0, sh1, sh2, sh3, th0, th1, th2, th3;
    half8v xm0, xm1, xm2, xm3, hh0, hh1, hh2, hh3;
    {
        const __half* p = Sh + rbase + lg * 8;
        LOAD_H4NT(p, sh0, sh1, sh2, sh3)
        p = Th + rbase + lg * 8;
        LOAD_H4NT(p, th0, th1, th2, th3)
        p = xm + rbase + lg * 8;
        LOAD_H4(p, xm0, xm1, xm2, xm3)
        if constexpr (DO_HY) {
            p = hIn + rbase + lg * 8;
            LOAD_H4(p, hh0, hh1, hh2, hh3)
        }
    }
    __builtin_amdgcn_sched_barrier(0);

    // ---- per col-tile: 2 W loads + 3-4 MFMA passes + immediate epilogue
#pragma unroll
    for (int c = 0; c < 8; ++c) {
        const __half* wlp = Wl + (size_t)(c * 16 + lr) * HID + lg * 8;
        const __half* wrp = Wr + (size_t)(c * 16 + lr) * HID + lg * 8;
        half8v l0, l1, l2, l3, r0, r1, r2, r3;
        LOAD_H4(wlp, l0, l1, l2, l3)
        LOAD_H4(wrp, r0, r1, r2, r3)
        float4v aS = {0.f, 0.f, 0.f, 0.f}, aT = aS, aZ = aS, aH = aS;
        MFMA4(l0, l1, l2, l3, sh0, sh1, sh2, sh3, aS)
        MFMA4(l0, l1, l2, l3, th0, th1, th2, th3, aT)
        MFMA4(r0, r1, r2, r3, xm0, xm1, xm2, xm3, aZ)
        if constexpr (DO_HY) {
            MFMA4(r0, r1, r2, r3, hh0, hh1, hh2, hh3, aH)
        }
        const int col0 = c * 16 + lg * 4;
        const float4v bv = *(const float4v*)(bias + col0);
        __half xm4[4], h4[4];
#pragma unroll
        for (int i = 0; i < 4; ++i) {
            const float z = aZ[i] + bv[i];
            const float xa = fmaxf(aS[i] + z, 0.f);
            const float xb = fmaxf(aT[i] + z, 0.f);
            xm4[i] = __float2half(rr * xa + (1.f - rr) * xb);
            if constexpr (DO_HY) h4[i] = __float2half(fmaxf(aS[i] + aH[i] + bv[i], 0.f));
        }
        uint2 xmv;
        xmv.x = h2u(__half2{xm4[0], xm4[1]});
        xmv.y = h2u(__half2{xm4[2], xm4[3]});
        if constexpr (DO_HY) {
            uint2 hv;
            hv.x = h2u(__half2{h4[0], h4[1]});
            hv.y = h2u(__half2{h4[2], h4[3]});
            *(uint2*)(xm + rbase + col0) = xmv;
            *(uint2*)(hOut + rbase + col0) = hv;
        } else {
            *(uint2*)(&hs[lr][col0]) = xmv;
        }
    }

    if constexpr (!DO_HY) {
        __syncthreads();
        const __half* lp = &hs[lr][lg * 8];
        half8v c0, c1, c2, c3;
        LOAD_H4(lp, c0, c1, c2, c3)
        float lv[3][4];
        float mx = -INFINITY;
#pragma unroll
        for (int c = 0; c < 3; ++c) {
            const __half* wq = WoT + (size_t)(c * 16 + lr) * HID + lg * 8;
            half8v w0, w1, w2, w3;
            LOAD_H4(wq, w0, w1, w2, w3)
            float4v t = {0.f, 0.f, 0.f, 0.f};
            MFMA4(w0, w1, w2, w3, c0, c1, c2, c3, t)
            const int col0 = c * 16 + lg * 4;
            const bool valid = col0 < NCLS;
#pragma unroll
            for (int i = 0; i < 4; ++i) {
                const float l = valid ? (t[i] + bout[col0 + i]) : -INFINITY;
                lv[c][i] = l;
                mx = fmaxf(mx, l);
            }
        }
        mx = fmaxf(mx, __shfl_xor(mx, 16));
        mx = fmaxf(mx, __shfl_xor(mx, 32));
        float sum = 0.f;
#pragma unroll
        for (int c = 0; c < 3; ++c)
#pragma unroll
            for (int i = 0; i < 4; ++i)
                if (lv[c][i] > -INFINITY) sum += expf(lv[c][i] - mx);
        sum += __shfl_xor(sum, 16);
        sum += __shfl_xor(sum, 32);
        const float lse = mx + logf(sum);
#pragma unroll
        for (int c = 0; c < 3; ++c) {
            const int col0 = c * 16 + lg * 4;
            if (col0 < NCLS) {
                float4 o = make_float4(lv[c][0] - lse, lv[c][1] - lse,
                                       lv[c][2] - lse, lv[c][3] - lse);
                *(float4*)(out + (size_t)row * NCLS + col0) = o;
            }
        }
    }
}

// ---------------------------------------------------------------------------
extern "C" void kernel_launch(void* const* d_in, const int* in_sizes, int n_in,
                              void* d_out, int out_size, void* d_ws, size_t ws_size,
                              hipStream_t stream) {
    const float* x0   = (const float*)d_in[0];
    const int*   arow = (const int*)d_in[1];
    const int*   acol = (const int*)d_in[2];
    const float* aval = (const float*)d_in[3];
    const int*   brow = (const int*)d_in[4];
    const int*   bcol = (const int*)d_in[5];
    const float* bval = (const float*)d_in[6];
    const float* mixr = (const float*)d_in[7];
    const int*   id   = (const int*)d_in[8];
    const float* Wl   = (const float*)d_in[9];
    const float* Wr   = (const float*)d_in[10];
    const float* bs   = (const float*)d_in[11];
    const float* Wout = (const float*)d_in[12];
    const float* bout = (const float*)d_in[13];
    float* out = (float*)d_out;

    const size_t NF = (size_t)NNODES * HID;   // 6.4M
    __half* x0h = (__half*)d_ws;
    __half* xmh = x0h + NF;
    __half* h1  = xmh + NF;
    __half* h2  = h1 + NF;
    __half* Sh  = h2 + NF;
    __half* Th  = Sh + NF;
    __half* Wt  = Th + NF;                    // 6 * 16384 f16
    __half* WoT = Wt + 6 * 16384;             // 48 * 128 f16
    int2* cvA = (int2*)(WoT + 48 * 128);      // E int2
    int2* cvB = cvA + NEDGES;
    int* rpa = (int*)(cvB + NEDGES);
    int* rpb = rpa + (NNODES + 1);

    const int gE = (NEDGES + 255) / 256;      // 1954
    const int gC = NNODES * HID / 4 / 256;    // 6250
    const int gG = NNODES / 16;               // 3125 (exact)
    const int gS2 = 2 * NNODES * 64 / 256;    // 25000

    prep_edges_kernel<<<4 * gE, 256, 0, stream>>>(arow, acol, aval, brow, bcol, bval,
                                                  id, rpa, rpb, cvA, cvB, gE);
    prep_x_kernel<<<gC, 256, 0, stream>>>((const float4*)x0, id, mixr,
                                          (uint2*)x0h, (uint2*)xmh);
    prep_w_kernel<<<(6 * 16384 + 48 * 128) / 256, 256, 0, stream>>>(Wl, Wr, Wout, Wt, WoT);

    // ---- layer 0 (aggr source = x0)
    spmm2_kernel<<<gS2, 256, 0, stream>>>(x0h, cvA, rpa, Sh, cvB, rpb, Th);
    fused_layer_kernel<true><<<gG, 64, 0, stream>>>(
        Sh, Th, xmh, x0h, Wt + 0 * 16384, Wt + 3 * 16384, bs, mixr,
        h1, nullptr, nullptr, nullptr);

    // ---- layer 1 (aggr source = h1)
    spmm2_kernel<<<gS2, 256, 0, stream>>>(h1, cvA, rpa, Sh, cvB, rpb, Th);
    fused_layer_kernel<true><<<gG, 64, 0, stream>>>(
        Sh, Th, xmh, h1, Wt + 1 * 16384, Wt + 4 * 16384, bs + 128, mixr,
        h2, nullptr, nullptr, nullptr);

    // ---- layer 2 (+ head, aggr source = h2)
    spmm2_kernel<<<gS2, 256, 0, stream>>>(h2, cvA, rpa, Sh, cvB, rpb, Th);
    fused_layer_kernel<false><<<gG, 64, 0, stream>>>(
        Sh, Th, xmh, nullptr, Wt + 2 * 16384, Wt + 5 * 16384, bs + 256, mixr,
        nullptr, WoT, bout, out);
}

// Round 13
// 215.809 us; speedup vs baseline: 1.3398x; 1.1785x over previous
//
#include <hip/hip_runtime.h>
#include <hip/hip_fp16.h>
#include <math.h>

#define NNODES 50000
#define NEDGES 500000
#define HID 128
#define NCLS 40

using half8v = __attribute__((ext_vector_type(8))) _Float16;
using float4v = __attribute__((ext_vector_type(4))) float;
using uint4v = __attribute__((ext_vector_type(4))) unsigned;

static __device__ __forceinline__ unsigned h2u(__half2 h) {
    union { __half2 h; unsigned u; } x; x.h = h; return x.u;
}
static __device__ __forceinline__ __half2 u2h(unsigned u) {
    union { unsigned u; __half2 h; } x; x.u = u; return x.h;
}

// ---------------------------------------------------------------------------
// prep_edges: rowptrs for A/B + interleaved {col, val-as-half2} streams
// ---------------------------------------------------------------------------
static __device__ __forceinline__ void rowptr_body(const int* __restrict__ row,
                                                   int e, int* __restrict__ rp) {
    if (e >= NEDGES) return;
    int r = row[e];
    int prev = (e == 0) ? -1 : row[e - 1];
    for (int q = prev + 1; q <= r; ++q) rp[q] = e;
    if (e == NEDGES - 1) {
        for (int q = r + 1; q <= NNODES; ++q) rp[q] = NEDGES;
    }
}

static __global__ void prep_edges_kernel(const int* __restrict__ arow,
                                         const int* __restrict__ acol,
                                         const float* __restrict__ aval,
                                         const int* __restrict__ brow,
                                         const int* __restrict__ bcol,
                                         const float* __restrict__ bval,
                                         const int* __restrict__ id,
                                         int* __restrict__ rpa, int* __restrict__ rpb,
                                         int2* __restrict__ cvA, int2* __restrict__ cvB,
                                         int gE) {
    int bid = blockIdx.x;
    if (bid < gE) {
        rowptr_body(arow, bid * 256 + threadIdx.x, rpa);
    } else if (bid < 2 * gE) {
        rowptr_body(brow, (bid - gE) * 256 + threadIdx.x, rpb);
    } else if (bid < 3 * gE) {
        int e = (bid - 2 * gE) * 256 + threadIdx.x;
        if (e < NEDGES) {
            __half2 v = __float2half2_rn(aval[e]);
            cvA[e] = make_int2(acol[e], (int)h2u(v));
        }
    } else {
        int e = (bid - 3 * gE) * 256 + threadIdx.x;
        if (e < NEDGES) {
            __half2 v = __float2half2_rn(bval[e]);
            cvB[e] = make_int2(id[bcol[e]], (int)h2u(v));
        }
    }
}

// ---------------------------------------------------------------------------
// prep_x: x0h = f16(x0); xmh = f16(r*x0 + (1-r)*x0[id])
// ---------------------------------------------------------------------------
static __global__ void prep_x_kernel(const float4* __restrict__ x, const int* __restrict__ id,
                                     const float* __restrict__ mixr,
                                     uint2* __restrict__ x0h, uint2* xmh) {
    int i = blockIdx.x * blockDim.x + threadIdx.x;   // exactly N*HID/4
    int n = i >> 5, qq = i & 31;
    float r = mixr[0];
    float4 a = x[i];
    float4 b = x[(size_t)id[n] * 32 + qq];
    uint2 pa, pm;
    pa.x = h2u(__floats2half2_rn(a.x, a.y));
    pa.y = h2u(__floats2half2_rn(a.z, a.w));
    pm.x = h2u(__floats2half2_rn(r * a.x + (1.f - r) * b.x, r * a.y + (1.f - r) * b.y));
    pm.y = h2u(__floats2half2_rn(r * a.z + (1.f - r) * b.z, r * a.w + (1.f - r) * b.w));
    x0h[i] = pa;
    xmh[i] = pm;
}

// ---------------------------------------------------------------------------
// prep_w: Wt[mat][n][k] f16 for 6 mats (0-2 Wl, 3-5 Wr), then WoT[c][k] 48-pad
// ---------------------------------------------------------------------------
static __global__ void prep_w_kernel(const float* __restrict__ Wl, const float* __restrict__ Wr,
                                     const float* __restrict__ Wout,
                                     __half* __restrict__ Wt, __half* __restrict__ WoT) {
    int t = blockIdx.x * blockDim.x + threadIdx.x;   // exactly 6*16384 + 48*128
    if (t < 6 * 16384) {
        int mat = t >> 14, idx = t & 16383;
        int n = idx >> 7, k = idx & 127;
        const float* src = (mat < 3) ? (Wl + mat * 16384) : (Wr + (mat - 3) * 16384);
        Wt[t] = __float2half(src[k * HID + n]);
    } else {
        int u = t - 6 * 16384;
        int c = u >> 7, k = u & 127;
        WoT[u] = (c < NCLS) ? __float2half(Wout[k * NCLS + c]) : __float2half(0.f);
    }
}

// ---------------------------------------------------------------------------
// spmm2: wave w<N -> Sh[w,:] via A edges; w>=N -> Th via B edges (h f16 in/out).
// Quarter-wave (16 lanes x 16B) per row gather, cv prefetched 1-ahead,
// __hfma2 accumulate, non-temporal output stores.
// ---------------------------------------------------------------------------
static __global__ __launch_bounds__(256) void spmm2_kernel(
    const __half* __restrict__ h,
    const int2* __restrict__ cvA, const int* __restrict__ rpA,
    __half* __restrict__ Sh,
    const int2* __restrict__ cvB, const int* __restrict__ rpB,
    __half* __restrict__ Th) {
    int w = blockIdx.x * 4 + (threadIdx.x >> 6);
    const int l = threadIdx.x & 63;
    const int q = l >> 4, j = l & 15;
    const int2* cv; const int* rp; __half* dst; int node;
    if (w < NNODES) { cv = cvA; rp = rpA; dst = Sh; node = w; }
    else            { cv = cvB; rp = rpB; dst = Th; node = w - NNODES; }
    const int e0 = rp[node], e1 = rp[node + 1];
    __half2 a0 = __float2half2_rn(0.f), a1 = a0, a2 = a0, a3 = a0;
    int e = e0 + q;
    int2 m0, m1;
    bool have = (e + 4 < e1);
    if (have) { m0 = cv[e]; m1 = cv[e + 4]; }
    while (have) {
        const int e2 = e + 8;
        const bool nxt = (e2 + 4 < e1);
        int2 k0 = m0, k1 = m1;
        if (nxt) { k0 = cv[e2]; k1 = cv[e2 + 4]; }
        const uint4 p0 = *(const uint4*)(h + (size_t)m0.x * HID + j * 8);
        const uint4 p1 = *(const uint4*)(h + (size_t)m1.x * HID + j * 8);
        const __half2 v0 = u2h((unsigned)m0.y), v1 = u2h((unsigned)m1.y);
        a0 = __hfma2(u2h(p0.x), v0, a0); a1 = __hfma2(u2h(p0.y), v0, a1);
        a2 = __hfma2(u2h(p0.z), v0, a2); a3 = __hfma2(u2h(p0.w), v0, a3);
        a0 = __hfma2(u2h(p1.x), v1, a0); a1 = __hfma2(u2h(p1.y), v1, a1);
        a2 = __hfma2(u2h(p1.z), v1, a2); a3 = __hfma2(u2h(p1.w), v1, a3);
        m0 = k0; m1 = k1; e = e2; have = nxt;
    }
    if (e < e1) {
        const int2 m = cv[e];
        const uint4 p = *(const uint4*)(h + (size_t)m.x * HID + j * 8);
        const __half2 v = u2h((unsigned)m.y);
        a0 = __hfma2(u2h(p.x), v, a0); a1 = __hfma2(u2h(p.y), v, a1);
        a2 = __hfma2(u2h(p.z), v, a2); a3 = __hfma2(u2h(p.w), v, a3);
    }
    a0 = __hadd2(a0, u2h(__shfl_xor((int)h2u(a0), 16)));
    a1 = __hadd2(a1, u2h(__shfl_xor((int)h2u(a1), 16)));
    a2 = __hadd2(a2, u2h(__shfl_xor((int)h2u(a2), 16)));
    a3 = __hadd2(a3, u2h(__shfl_xor((int)h2u(a3), 16)));
    a0 = __hadd2(a0, u2h(__shfl_xor((int)h2u(a0), 32)));
    a1 = __hadd2(a1, u2h(__shfl_xor((int)h2u(a1), 32)));
    a2 = __hadd2(a2, u2h(__shfl_xor((int)h2u(a2), 32)));
    a3 = __hadd2(a3, u2h(__shfl_xor((int)h2u(a3), 32)));
    if (l < 16) {
        uint4v o;
        o.x = h2u(a0); o.y = h2u(a1); o.z = h2u(a2); o.w = h2u(a3);
        __builtin_nontemporal_store(o, (uint4v*)(dst + (size_t)node * HID + l * 8));
    }
}

// ---------------------------------------------------------------------------
// Swapped-operand f16 MFMA: D[row = lane&15][col = tile*16 + (lane>>4)*4 + i]
// ---------------------------------------------------------------------------
#define LOAD_H4(ptr, w0, w1, w2, w3)                                            \
    w0 = *(const half8v*)(ptr);                                                 \
    w1 = *(const half8v*)((ptr) + 32);                                          \
    w2 = *(const half8v*)((ptr) + 64);                                          \
    w3 = *(const half8v*)((ptr) + 96);

#define LOAD_H4NT(ptr, w0, w1, w2, w3)                                          \
    w0 = __builtin_nontemporal_load((const half8v*)(ptr));                      \
    w1 = __builtin_nontemporal_load((const half8v*)((ptr) + 32));               \
    w2 = __builtin_nontemporal_load((const half8v*)((ptr) + 64));               \
    w3 = __builtin_nontemporal_load((const half8v*)((ptr) + 96));

#define MFMA4(w0, w1, w2, w3, x0, x1, x2, x3, t)                                \
    t = __builtin_amdgcn_mfma_f32_16x16x32_f16(w0, x0, t, 0, 0, 0);             \
    t = __builtin_amdgcn_mfma_f32_16x16x32_f16(w1, x1, t, 0, 0, 0);             \
    t = __builtin_amdgcn_mfma_f32_16x16x32_f16(w2, x2, t, 0, 0, 0);             \
    t = __builtin_amdgcn_mfma_f32_16x16x32_f16(w3, x3, t, 0, 0, 0);

// ---------------------------------------------------------------------------
// fused_layer<DO_HY>: 256 threads / 64 rows (4 waves x 16-row stripes).
// Per col-tile c: 256 threads cooperatively stage Wl/Wr tile c (8 KB) into
// double-buffered LDS (coalesced half8v each); global prefetch of tile c+1
// issued before the barrier; waves MFMA their own A-fragments vs LDS W.
//   S = Sh@Wl; T = Th@Wl; z = xm@Wr + b; DO_HY: hz = hIn@Wr
//   h' = relu(S + hz + b);  xm' = r*relu(S+z) + (1-r)*relu(T+z)
//   !DO_HY: xm' -> hs LDS; head: logits = xm'@WoT + bout; log_softmax -> out
// ---------------------------------------------------------------------------
template <bool DO_HY>
static __global__ __launch_bounds__(256, 2) void fused_layer_kernel(
    const __half* __restrict__ Sh, const __half* __restrict__ Th,
    __half* xm, const __half* __restrict__ hIn,
    const __half* __restrict__ Wl, const __half* __restrict__ Wr,
    const float* __restrict__ bias, const float* __restrict__ mixr,
    __half* __restrict__ hOut,
    const __half* __restrict__ WoT, const float* __restrict__ bout,
    float* __restrict__ out) {
    __shared__ __align__(16) _Float16 Wls[2][16][136];
    __shared__ __align__(16) _Float16 Wrs[2][16][136];
    __shared__ __align__(16) __half hs[DO_HY ? 1 : 64][136];
    const int tid = threadIdx.x;
    const int lr = tid & 15;
    const int lg = (tid >> 4) & 3;
    const int wv = tid >> 6;
    const int row = blockIdx.x * 64 + wv * 16 + lr;
    const int rowc = min(row, NNODES - 1);
    const size_t rbase = (size_t)rowc * HID;
    const float rr = mixr[0];
    // staging coords: thread t handles tile elements [t>>4][(t&15)*8 .. +7]
    const int srow = tid >> 4, scol = (tid & 15) * 8;

    // ---- A-stream fragments (issued first; fly under the staging prologue)
    half8v sh0, sh1, sh2, sh3, th0, th1, th2, th3;
    half8v xm0, xm1, xm2, xm3, hh0, hh1, hh2, hh3;
    {
        const __half* p = Sh + rbase + lg * 8;
        LOAD_H4NT(p, sh0, sh1, sh2, sh3)
        p = Th + rbase + lg * 8;
        LOAD_H4NT(p, th0, th1, th2, th3)
        p = xm + rbase + lg * 8;
        LOAD_H4(p, xm0, xm1, xm2, xm3)
        if constexpr (DO_HY) {
            p = hIn + rbase + lg * 8;
            LOAD_H4(p, hh0, hh1, hh2, hh3)
        }
    }

    // ---- W staging prologue: tile 0 into registers
    half8v wlreg = *(const half8v*)(Wl + srow * HID + scol);
    half8v wrreg = *(const half8v*)(Wr + srow * HID + scol);

#pragma unroll
    for (int c = 0; c < 8; ++c) {
        const int buf = c & 1;
        *(half8v*)&Wls[buf][srow][scol] = wlreg;
        *(half8v*)&Wrs[buf][srow][scol] = wrreg;
        if (c < 7) {   // prefetch tile c+1 (flies during barrier + MFMA)
            wlreg = *(const half8v*)(Wl + (c + 1) * 2048 + srow * HID + scol);
            wrreg = *(const half8v*)(Wr + (c + 1) * 2048 + srow * HID + scol);
        }
        __syncthreads();

        // W fragments from LDS (2-way bank alias only: row stride 272B)
        const _Float16* wlp = &Wls[buf][lr][lg * 8];
        const _Float16* wrp = &Wrs[buf][lr][lg * 8];
        half8v l0, l1, l2, l3, r0, r1, r2, r3;
        LOAD_H4(wlp, l0, l1, l2, l3)
        LOAD_H4(wrp, r0, r1, r2, r3)
        float4v aS = {0.f, 0.f, 0.f, 0.f}, aT = aS, aZ = aS, aH = aS;
        MFMA4(l0, l1, l2, l3, sh0, sh1, sh2, sh3, aS)
        MFMA4(l0, l1, l2, l3, th0, th1, th2, th3, aT)
        MFMA4(r0, r1, r2, r3, xm0, xm1, xm2, xm3, aZ)
        if constexpr (DO_HY) {
            MFMA4(r0, r1, r2, r3, hh0, hh1, hh2, hh3, aH)
        }
        const int col0 = c * 16 + lg * 4;
        const float4v bv = *(const float4v*)(bias + col0);
        __half xm4[4], h4[4];
#pragma unroll
        for (int i = 0; i < 4; ++i) {
            const float z = aZ[i] + bv[i];
            const float xa = fmaxf(aS[i] + z, 0.f);
            const float xb = fmaxf(aT[i] + z, 0.f);
            xm4[i] = __float2half(rr * xa + (1.f - rr) * xb);
            if constexpr (DO_HY) h4[i] = __float2half(fmaxf(aS[i] + aH[i] + bv[i], 0.f));
        }
        uint2 xmv;
        xmv.x = h2u(__half2{xm4[0], xm4[1]});
        xmv.y = h2u(__half2{xm4[2], xm4[3]});
        if constexpr (DO_HY) {
            uint2 hv;
            hv.x = h2u(__half2{h4[0], h4[1]});
            hv.y = h2u(__half2{h4[2], h4[3]});
            if (row < NNODES) {
                *(uint2*)(xm + rbase + col0) = xmv;
                *(uint2*)(hOut + rbase + col0) = hv;
            }
        } else {
            *(uint2*)(&hs[wv * 16 + lr][col0]) = xmv;
        }
        __syncthreads();   // all reads of buf done before iter c+2 overwrites
    }

    if constexpr (!DO_HY) {
        // head: logits = xm' @ WoT + bout; log_softmax per row
        const __half* lp = &hs[wv * 16 + lr][lg * 8];
        half8v c0, c1, c2, c3;
        LOAD_H4(lp, c0, c1, c2, c3)
        float lv[3][4];
        float mx = -INFINITY;
#pragma unroll
        for (int c = 0; c < 3; ++c) {
            const __half* wq = WoT + (size_t)(c * 16 + lr) * HID + lg * 8;
            half8v w0, w1, w2, w3;
            LOAD_H4(wq, w0, w1, w2, w3)
            float4v t = {0.f, 0.f, 0.f, 0.f};
            MFMA4(w0, w1, w2, w3, c0, c1, c2, c3, t)
            const int col0 = c * 16 + lg * 4;
            const bool valid = col0 < NCLS;
#pragma unroll
            for (int i = 0; i < 4; ++i) {
                const float l = valid ? (t[i] + bout[col0 + i]) : -INFINITY;
                lv[c][i] = l;
                mx = fmaxf(mx, l);
            }
        }
        mx = fmaxf(mx, __shfl_xor(mx, 16));
        mx = fmaxf(mx, __shfl_xor(mx, 32));
        float sum = 0.f;
#pragma unroll
        for (int c = 0; c < 3; ++c)
#pragma unroll
            for (int i = 0; i < 4; ++i)
                if (lv[c][i] > -INFINITY) sum += expf(lv[c][i] - mx);
        sum += __shfl_xor(sum, 16);
        sum += __shfl_xor(sum, 32);
        const float lse = mx + logf(sum);
#pragma unroll
        for (int c = 0; c < 3; ++c) {
            const int col0 = c * 16 + lg * 4;
            if (col0 < NCLS && row < NNODES) {
                float4 o = make_float4(lv[c][0] - lse, lv[c][1] - lse,
                                       lv[c][2] - lse, lv[c][3] - lse);
                *(float4*)(out + (size_t)row * NCLS + col0) = o;
            }
        }
    }
}

// ---------------------------------------------------------------------------
extern "C" void kernel_launch(void* const* d_in, const int* in_sizes, int n_in,
                              void* d_out, int out_size, void* d_ws, size_t ws_size,
                              hipStream_t stream) {
    const float* x0   = (const float*)d_in[0];
    const int*   arow = (const int*)d_in[1];
    const int*   acol = (const int*)d_in[2];
    const float* aval = (const float*)d_in[3];
    const int*   brow = (const int*)d_in[4];
    const int*   bcol = (const int*)d_in[5];
    const float* bval = (const float*)d_in[6];
    const float* mixr = (const float*)d_in[7];
    const int*   id   = (const int*)d_in[8];
    const float* Wl   = (const float*)d_in[9];
    const float* Wr   = (const float*)d_in[10];
    const float* bs   = (const float*)d_in[11];
    const float* Wout = (const float*)d_in[12];
    const float* bout = (const float*)d_in[13];
    float* out = (float*)d_out;

    const size_t NF = (size_t)NNODES * HID;   // 6.4M
    __half* x0h = (__half*)d_ws;
    __half* xmh = x0h + NF;
    __half* h1  = xmh + NF;
    __half* h2  = h1 + NF;
    __half* Sh  = h2 + NF;
    __half* Th  = Sh + NF;
    __half* Wt  = Th + NF;                    // 6 * 16384 f16
    __half* WoT = Wt + 6 * 16384;             // 48 * 128 f16
    int2* cvA = (int2*)(WoT + 48 * 128);      // E int2
    int2* cvB = cvA + NEDGES;
    int* rpa = (int*)(cvB + NEDGES);
    int* rpb = rpa + (NNODES + 1);

    const int gE = (NEDGES + 255) / 256;      // 1954
    const int gC = NNODES * HID / 4 / 256;    // 6250
    const int gG = (NNODES + 63) / 64;        // 782
    const int gS2 = 2 * NNODES * 64 / 256;    // 25000

    prep_edges_kernel<<<4 * gE, 256, 0, stream>>>(arow, acol, aval, brow, bcol, bval,
                                                  id, rpa, rpb, cvA, cvB, gE);
    prep_x_kernel<<<gC, 256, 0, stream>>>((const float4*)x0, id, mixr,
                                          (uint2*)x0h, (uint2*)xmh);
    prep_w_kernel<<<(6 * 16384 + 48 * 128) / 256, 256, 0, stream>>>(Wl, Wr, Wout, Wt, WoT);

    // ---- layer 0 (aggr source = x0)
    spmm2_kernel<<<gS2, 256, 0, stream>>>(x0h, cvA, rpa, Sh, cvB, rpb, Th);
    fused_layer_kernel<true><<<gG, 256, 0, stream>>>(
        Sh, Th, xmh, x0h, Wt + 0 * 16384, Wt + 3 * 16384, bs, mixr,
        h1, nullptr, nullptr, nullptr);

    // ---- layer 1 (aggr source = h1)
    spmm2_kernel<<<gS2, 256, 0, stream>>>(h1, cvA, rpa, Sh, cvB, rpb, Th);
    fused_layer_kernel<true><<<gG, 256, 0, stream>>>(
        Sh, Th, xmh, h1, Wt + 1 * 16384, Wt + 4 * 16384, bs + 128, mixr,
        h2, nullptr, nullptr, nullptr);

    // ---- layer 2 (+ head, aggr source = h2)
    spmm2_kernel<<<gS2, 256, 0, stream>>>(h2, cvA, rpa, Sh, cvB, rpb, Th);
    fused_layer_kernel<false><<<gG, 256, 0, stream>>>(
        Sh, Th, xmh, nullptr, Wt + 2 * 16384, Wt + 5 * 16384, bs + 256, mixr,
        nullptr, WoT, bout, out);
}